// Round 3
// baseline (9427.576 us; speedup 1.0000x reference)
//
#include <hip/hip_runtime.h>
#include <math.h>

// Problem constants (fixed by the reference): N=6000, D=256, H=8, DH=32, P=128, B=16
#define N_GENES 6000
#define DM 256
#define NH 8
#define DHEAD 32
#define FF 1024
#define PMAX 128
#define RPB 4   // rows per block in FFN kernel (B*N = 96000 divisible by 4)

typedef unsigned short u16;
typedef unsigned int u32;

__device__ __forceinline__ float bf2f(u16 u) { return __uint_as_float(((u32)u) << 16); }
__device__ __forceinline__ u16 f2bf(float f) {
    u32 x = __float_as_uint(f);
    return (u16)((x + 0x7fffu + ((x >> 16) & 1u)) >> 16);  // RNE
}

// dtype-generic element/vec4 accessors
__device__ __forceinline__ float ldx(const u16* p, size_t i) { return bf2f(p[i]); }
__device__ __forceinline__ float ldx(const float* p, size_t i) { return p[i]; }
__device__ __forceinline__ float4 ld4(const u16* p) {
    ushort4 w = *(const ushort4*)p;
    return make_float4(bf2f(w.x), bf2f(w.y), bf2f(w.z), bf2f(w.w));
}
__device__ __forceinline__ float4 ld4(const float* p) { return *(const float4*)p; }
__device__ __forceinline__ void stx(u16* p, size_t i, float v) { p[i] = f2bf(v); }
__device__ __forceinline__ void stx(float* p, size_t i, float v) { p[i] = v; }

__device__ __forceinline__ float gelu_exact(float x) {
    return 0.5f * x * (1.0f + erff(x * 0.70710678118654752f));
}

// block = 256 threads (4 waves)
__device__ __forceinline__ float block_reduce_sum256(float v, float* scratch) {
    #pragma unroll
    for (int off = 32; off > 0; off >>= 1) v += __shfl_down(v, off, 64);
    int tid = threadIdx.x;
    if ((tid & 63) == 0) scratch[tid >> 6] = v;
    __syncthreads();
    float s = scratch[0] + scratch[1] + scratch[2] + scratch[3];
    __syncthreads();
    return s;
}

// ---------------- dtype detector: flag=1 if H_genes is bf16, 0 if float32 ----------------
// fp32 data read as u16 pairs: even words are mantissa bits -> ~44% have wild bf16
// exponents (>=2^65 or <=2^-78). Real bf16 N(0,1) data: none.
__global__ void detect_kernel(const void* H, int* flag) {
    const u16* p = (const u16*)H;
    int tid = threadIdx.x;
    u16 u = p[tid];
    int e = (u >> 7) & 0xFF;
    bool sus = (e >= 0xC0) || (e <= 0x30 && (u & 0x7FFFu) != 0);
    unsigned long long m = __ballot(sus);
    if (tid == 0) flag[0] = (__popcll(m) < 4) ? 1 : 0;
}

// ---------------- q projection ----------------
template <typename T>
__device__ __forceinline__ void qproj_body(
    const T* Hg, const T* Win, const T* bin, float* q, float* xs) {
    int n = blockIdx.x, d = threadIdx.x;
    xs[d] = ldx(Hg, (size_t)n * DM + d);
    __syncthreads();
    const T* wrow = Win + (size_t)d * DM;  // Wq rows [0,DM)
    float acc = ldx(bin, d);
    #pragma unroll 4
    for (int k = 0; k < DM; k += 4) {
        float4 w = ld4(wrow + k);
        acc += w.x * xs[k] + w.y * xs[k + 1] + w.z * xs[k + 2] + w.w * xs[k + 3];
    }
    q[(size_t)n * DM + d] = acc;
}
__global__ __launch_bounds__(256) void qproj_kernel(
    const void* Hg, const void* Win, const void* bin, float* q, const int* flag) {
    __shared__ float xs[DM];
    if (*flag) qproj_body((const u16*)Hg, (const u16*)Win, (const u16*)bin, q, xs);
    else       qproj_body((const float*)Hg, (const float*)Win, (const float*)bin, q, xs);
}

// ---------------- k/v projection for the P gathered rows ----------------
template <typename T>
__device__ __forceinline__ void kvproj_body(
    const T* Hg, const int* pidx, const T* Win, const T* bin,
    float* kbuf, float* vbuf, float* xs) {
    int p = blockIdx.x, d = threadIdx.x;
    int row = pidx[p];
    xs[d] = ldx(Hg, (size_t)row * DM + d);
    __syncthreads();
    const T* wk = Win + (size_t)(DM + d) * DM;       // Wk rows [DM,2DM)
    const T* wv = Win + (size_t)(2 * DM + d) * DM;   // Wv rows [2DM,3DM)
    float ak = ldx(bin, DM + d);
    float av = ldx(bin, 2 * DM + d);
    #pragma unroll 4
    for (int k = 0; k < DM; k += 4) {
        float4 a = ld4(wk + k);
        float4 b = ld4(wv + k);
        ak += a.x * xs[k] + a.y * xs[k + 1] + a.z * xs[k + 2] + a.w * xs[k + 3];
        av += b.x * xs[k] + b.y * xs[k + 1] + b.z * xs[k + 2] + b.w * xs[k + 3];
    }
    kbuf[(size_t)p * DM + d] = ak;
    vbuf[(size_t)p * DM + d] = av;
}
__global__ __launch_bounds__(256) void kvproj_kernel(
    const void* Hg, const int* pidx, const void* Win, const void* bin,
    float* kbuf, float* vbuf, const int* flag) {
    __shared__ float xs[DM];
    if (*flag) kvproj_body((const u16*)Hg, pidx, (const u16*)Win, (const u16*)bin, kbuf, vbuf, xs);
    else       kvproj_body((const float*)Hg, pidx, (const float*)Win, (const float*)bin, kbuf, vbuf, xs);
}

// ---- attention + out-proj + residual + LN1, one block per (n,b); x staged in d_out ----
// smem layout: qs[256] | hrow[256] | sc[8][129] | ctxs[256] | asg[128] | red[4]
#define ATTN_SMEM_BYTES (1024 + 1024 + 4128 + 1024 + 512 + 16)

template <typename T, bool INLINE_Q>
__device__ __forceinline__ void attn_body(
    const T* Hg, const float* q, const float* kbuf, const float* vbuf,
    const int* assign, const T* Win, const T* bin,
    const T* Wout, const T* bout, const T* ln1g, const T* ln1b,
    T* xout, int P, char* smem) {
    float* qs   = (float*)smem;
    float* hrow = qs + DM;
    float (*sc)[PMAX + 1] = (float(*)[PMAX + 1])(hrow + DM);
    float* ctxs = (float*)(smem + 1024 + 1024 + 4128);
    int*   asg  = (int*)(ctxs + DM);
    float* red  = (float*)(asg + PMAX);

    int n = blockIdx.x, b = blockIdx.y, tid = threadIdx.x;
    if (tid < P) asg[tid] = assign[tid];
    hrow[tid] = ldx(Hg, (size_t)n * DM + tid);
    if (!INLINE_Q) qs[tid] = q[(size_t)n * DM + tid] * 0.17677669529663687f;  // 1/sqrt(32)
    __syncthreads();

    if (INLINE_Q) {
        float acc = ldx(bin, tid);
        const T* wrow = Win + (size_t)tid * DM;  // Wq rows [0,DM)
        #pragma unroll 4
        for (int k = 0; k < DM; k += 4) {
            float4 w = ld4(wrow + k);
            acc += w.x * hrow[k] + w.y * hrow[k + 1] + w.z * hrow[k + 2] + w.w * hrow[k + 3];
        }
        qs[tid] = acc * 0.17677669529663687f;
        __syncthreads();
    }

    // batch b owns contiguous key range [start, start+cnt) (assignment sorted)
    int start = 0, cnt = 0;
    for (int p = 0; p < P; ++p) { int a = asg[p]; start += (a < b); cnt += (a == b); }

    // scores[h][p] = (q*scale) . k
    for (int idx = tid; idx < NH * cnt; idx += 256) {
        int h = idx & (NH - 1);
        int pl = idx >> 3;
        const float* krow = kbuf + (size_t)(start + pl) * DM + h * DHEAD;
        const float* qh = qs + h * DHEAD;
        float acc = 0.f;
        #pragma unroll
        for (int e = 0; e < DHEAD; ++e) acc += qh[e] * krow[e];
        sc[h][pl] = acc;
    }
    __syncthreads();

    // per-head softmax over [0,cnt): 8 groups of 32 lanes
    if (cnt > 0) {
        int h = tid >> 5, l = tid & 31;
        float m = -INFINITY;
        for (int p = l; p < cnt; p += 32) m = fmaxf(m, sc[h][p]);
        #pragma unroll
        for (int off = 16; off > 0; off >>= 1) m = fmaxf(m, __shfl_xor(m, off, 32));
        float s = 0.f;
        for (int p = l; p < cnt; p += 32) { float e = __expf(sc[h][p] - m); sc[h][p] = e; s += e; }
        #pragma unroll
        for (int off = 16; off > 0; off >>= 1) s += __shfl_xor(s, off, 32);
        float inv = 1.0f / s;
        for (int p = l; p < cnt; p += 32) sc[h][p] *= inv;
    }
    __syncthreads();

    // ctx[h,e]: thread tid = h*32+e
    {
        int hh = tid >> 5, e = tid & 31;
        float acc = 0.f;
        for (int p = 0; p < cnt; ++p)
            acc += sc[hh][p] * vbuf[(size_t)(start + p) * DM + hh * DHEAD + e];
        ctxs[tid] = acc;
    }
    __syncthreads();

    // out-proj (entire attn output zeroed if batch empty: torch has_any semantics)
    float ao = 0.f;
    if (cnt > 0) {
        ao = ldx(bout, tid);
        const T* wrow = Wout + (size_t)tid * DM;
        #pragma unroll 4
        for (int k = 0; k < DM; k += 4) {
            float4 w = ld4(wrow + k);
            ao += w.x * ctxs[k] + w.y * ctxs[k + 1] + w.z * ctxs[k + 2] + w.w * ctxs[k + 3];
        }
    }

    // residual + LN1 -> x row staged in d_out
    float t = hrow[tid] + ao;
    float mu = block_reduce_sum256(t, red) * (1.0f / DM);
    float dv = t - mu;
    float var = block_reduce_sum256(dv * dv, red) * (1.0f / DM);
    float xv = dv * rsqrtf(var + 1e-5f) * ldx(ln1g, tid) + ldx(ln1b, tid);
    stx(xout, ((size_t)b * N_GENES + n) * DM + tid, xv);
}

template <bool INLINE_Q>
__global__ __launch_bounds__(256) void attn_kernel(
    const void* Hg, const float* q, const float* kbuf, const float* vbuf,
    const int* assign, const void* Win, const void* bin,
    const void* Wout, const void* bout, const void* ln1g, const void* ln1b,
    void* xout, int P, const int* flag) {
    __shared__ char smem[ATTN_SMEM_BYTES];
    if (*flag)
        attn_body<u16, INLINE_Q>((const u16*)Hg, q, kbuf, vbuf, assign,
            (const u16*)Win, (const u16*)bin, (const u16*)Wout, (const u16*)bout,
            (const u16*)ln1g, (const u16*)ln1b, (u16*)xout, P, smem);
    else
        attn_body<float, INLINE_Q>((const float*)Hg, q, kbuf, vbuf, assign,
            (const float*)Win, (const float*)bin, (const float*)Wout, (const float*)bout,
            (const float*)ln1g, (const float*)ln1b, (float*)xout, P, smem);
}

// ---------------- FFN + residual + LN2, RPB rows per block; in-place on d_out ----------------
// smem layout: xs[RPB][DM] (4096 B) | hs[RPB][FF] (16384 B) | red[4]
#define FFN_SMEM_BYTES (4096 + 16384 + 16)

template <typename T>
__device__ __forceinline__ void ffn_body(
    T* xio, const T* W1, const T* b1, const T* W2, const T* b2,
    const T* ln2g, const T* ln2b, char* smem) {
    float (*xs)[DM] = (float(*)[DM])smem;
    float (*hs)[FF] = (float(*)[FF])(smem + 4096);
    float* red = (float*)(smem + 4096 + 16384);

    int tid = threadIdx.x;
    size_t row0 = (size_t)blockIdx.x * RPB;

    for (int i = tid; i < RPB * DM; i += 256)
        ((float*)xs)[i] = ldx(xio, row0 * DM + i);
    __syncthreads();

    // GEMM1 + exact GELU: hidden[o] for o = oi*256 + tid; RPB rows share each W1-row read
    for (int oi = 0; oi < FF / 256; ++oi) {
        int o = oi * 256 + tid;
        float bb = ldx(b1, o);
        float a0 = bb, a1 = bb, a2 = bb, a3 = bb;
        const T* wrow = W1 + (size_t)o * DM;
        #pragma unroll 2
        for (int k = 0; k < DM; k += 4) {
            float4 w = ld4(wrow + k);
            a0 += w.x * xs[0][k] + w.y * xs[0][k + 1] + w.z * xs[0][k + 2] + w.w * xs[0][k + 3];
            a1 += w.x * xs[1][k] + w.y * xs[1][k + 1] + w.z * xs[1][k + 2] + w.w * xs[1][k + 3];
            a2 += w.x * xs[2][k] + w.y * xs[2][k + 1] + w.z * xs[2][k + 2] + w.w * xs[2][k + 3];
            a3 += w.x * xs[3][k] + w.y * xs[3][k + 1] + w.z * xs[3][k + 2] + w.w * xs[3][k + 3];
        }
        hs[0][o] = gelu_exact(a0);
        hs[1][o] = gelu_exact(a1);
        hs[2][o] = gelu_exact(a2);
        hs[3][o] = gelu_exact(a3);
    }
    __syncthreads();

    // GEMM2: out[d] for d = tid
    int d = tid;
    float bb2 = ldx(b2, d);
    float c0 = bb2, c1 = bb2, c2 = bb2, c3 = bb2;
    const T* wrow = W2 + (size_t)d * FF;
    #pragma unroll 2
    for (int k = 0; k < FF; k += 4) {
        float4 w = ld4(wrow + k);
        c0 += w.x * hs[0][k] + w.y * hs[0][k + 1] + w.z * hs[0][k + 2] + w.w * hs[0][k + 3];
        c1 += w.x * hs[1][k] + w.y * hs[1][k + 1] + w.z * hs[1][k + 2] + w.w * hs[1][k + 3];
        c2 += w.x * hs[2][k] + w.y * hs[2][k + 1] + w.z * hs[2][k + 2] + w.w * hs[2][k + 3];
        c3 += w.x * hs[3][k] + w.y * hs[3][k + 1] + w.z * hs[3][k + 2] + w.w * hs[3][k + 3];
    }
    float cr[RPB] = {c0, c1, c2, c3};

    float g = ldx(ln2g, d), bln = ldx(ln2b, d);
    #pragma unroll
    for (int r = 0; r < RPB; ++r) {
        float t = cr[r] + xs[r][d];
        float mu = block_reduce_sum256(t, red) * (1.0f / DM);
        float dvv = t - mu;
        float var = block_reduce_sum256(dvv * dvv, red) * (1.0f / DM);
        float y = dvv * rsqrtf(var + 1e-5f) * g + bln;
        stx(xio, (row0 + r) * DM + d, y);
    }
}
__global__ __launch_bounds__(256) void ffn_kernel(
    void* xio, const void* W1, const void* b1, const void* W2, const void* b2,
    const void* ln2g, const void* ln2b, const int* flag) {
    __shared__ char smem[FFN_SMEM_BYTES];
    if (*flag)
        ffn_body((u16*)xio, (const u16*)W1, (const u16*)b1, (const u16*)W2,
                 (const u16*)b2, (const u16*)ln2g, (const u16*)ln2b, smem);
    else
        ffn_body((float*)xio, (const float*)W1, (const float*)b1, (const float*)W2,
                 (const float*)b2, (const float*)ln2g, (const float*)ln2b, smem);
}

extern "C" void kernel_launch(void* const* d_in, const int* in_sizes, int n_in,
                              void* d_out, int out_size, void* d_ws, size_t ws_size,
                              hipStream_t stream) {
    const void* Hg    = d_in[0];
    const int* pidx   = (const int*)d_in[1];
    const int* assign = (const int*)d_in[2];
    // d_in[3] = batch_size (device scalar); B derived from out_size instead
    const void* in_w  = d_in[4];
    const void* in_b  = d_in[5];
    const void* out_w = d_in[6];
    const void* out_b = d_in[7];
    const void* w1    = d_in[8];
    const void* b1    = d_in[9];
    const void* w2    = d_in[10];
    const void* b2    = d_in[11];
    const void* g1    = d_in[12];
    const void* bb1   = d_in[13];
    const void* g2    = d_in[14];
    const void* bb2   = d_in[15];

    int P = in_sizes[1];
    int B = out_size / (N_GENES * DM);
    size_t nrows = (size_t)B * N_GENES;

    // ws layout: flag (16 B) | kbuf P*DM f32 | vbuf P*DM f32 | q N*DM f32 (optional)
    int* flag   = (int*)d_ws;
    float* kbuf = (float*)((char*)d_ws + 16);
    float* vbuf = kbuf + (size_t)P * DM;
    float* q    = vbuf + (size_t)P * DM;
    size_t need_q = 16 + 2 * (size_t)P * DM * 4 + (size_t)N_GENES * DM * 4;
    bool have_q = (ws_size >= need_q);

    detect_kernel<<<1, 64, 0, stream>>>(Hg, flag);
    kvproj_kernel<<<P, 256, 0, stream>>>(Hg, pidx, in_w, in_b, kbuf, vbuf, flag);

    if (have_q) {
        qproj_kernel<<<N_GENES, 256, 0, stream>>>(Hg, in_w, in_b, q, flag);
        attn_kernel<false><<<dim3(N_GENES, B), 256, 0, stream>>>(
            Hg, q, kbuf, vbuf, assign, in_w, in_b, out_w, out_b, g1, bb1, d_out, P, flag);
    } else {
        attn_kernel<true><<<dim3(N_GENES, B), 256, 0, stream>>>(
            Hg, nullptr, kbuf, vbuf, assign, in_w, in_b, out_w, out_b, g1, bb1, d_out, P, flag);
    }

    ffn_kernel<<<(unsigned)(nrows / RPB), 256, 0, stream>>>(
        d_out, w1, b1, w2, b2, g2, bb2, flag);
}

// Round 4
// 995.665 us; speedup vs baseline: 9.4686x; 9.4686x over previous
//
#include <hip/hip_runtime.h>
#include <math.h>

// Problem constants: N=6000, D=256, H=8, DH=32, P=128, B=16. fp32 in/out (established R3).
#define N_GENES 6000
#define DM 256
#define NH 8
#define DHEAD 32
#define FF 1024
#define PMAX 128
#define MT 32     // rows per block in fused tail
#define LDP 264   // padded LDS inner dim (+8 elems: breaks 16-way bank conflict on A-frag reads)

typedef unsigned short u16;
typedef unsigned int u32;
typedef __attribute__((ext_vector_type(8))) short s8bf;  // 8 bf16 in 4 VGPRs (guide-verified form)
typedef __attribute__((ext_vector_type(4))) float f4;

__device__ __forceinline__ f4 mfma_bf16(s8bf a, s8bf b, f4 c) {
    return __builtin_amdgcn_mfma_f32_16x16x32_bf16(a, b, c, 0, 0, 0);
}

__device__ __forceinline__ float bf2f(u16 u) { return __uint_as_float(((u32)u) << 16); }
__device__ __forceinline__ u16 f2bf(float f) {
    u32 x = __float_as_uint(f);
    return (u16)((x + 0x7fffu + ((x >> 16) & 1u)) >> 16);  // RNE
}
__device__ __forceinline__ float gelu_exact(float x) {
    return 0.5f * x * (1.0f + erff(x * 0.70710678118654752f));
}

// ---------------- fp32 -> bf16 weight conversion ----------------
__global__ __launch_bounds__(256) void cvt_kernel(const float* __restrict__ src,
                                                  u16* __restrict__ dst, int n) {
    int i = blockIdx.x * 256 + threadIdx.x;
    if (i < n) dst[i] = f2bf(src[i]);
}

// ---------------- k/v projection for the P gathered rows (fp32) ----------------
__global__ __launch_bounds__(256) void kvproj_kernel(
    const float* __restrict__ Hg, const int* __restrict__ pidx,
    const float* __restrict__ Win, const float* __restrict__ bin,
    float* __restrict__ kbuf, float* __restrict__ vbuf) {
    __shared__ float xs[DM];
    int p = blockIdx.x, d = threadIdx.x;
    int row = pidx[p];
    xs[d] = Hg[(size_t)row * DM + d];
    __syncthreads();
    const float4* wk = (const float4*)(Win + (size_t)(DM + d) * DM);
    const float4* wv = (const float4*)(Win + (size_t)(2 * DM + d) * DM);
    float ak = bin[DM + d];
    float av = bin[2 * DM + d];
    #pragma unroll 4
    for (int k = 0; k < DM / 4; ++k) {
        float4 a = wk[k], b = wv[k];
        float x0 = xs[4*k], x1 = xs[4*k+1], x2 = xs[4*k+2], x3 = xs[4*k+3];
        ak += a.x * x0 + a.y * x1 + a.z * x2 + a.w * x3;
        av += b.x * x0 + b.y * x1 + b.z * x2 + b.w * x3;
    }
    kbuf[(size_t)p * DM + d] = ak;
    vbuf[(size_t)p * DM + d] = av;
}

// ---- attention context, one block per gene n: all B batches at once ----
// inline q-proj; scores[8][128] once; slice-wise softmax; ctx -> d_out rows (fp32)
__global__ __launch_bounds__(256) void attn_ctx_kernel(
    const float* __restrict__ Hg, const float* __restrict__ Win,
    const float* __restrict__ bin, const float* __restrict__ kbuf,
    const float* __restrict__ vbuf, const int* __restrict__ assign,
    float* __restrict__ ctx_out, int P, int B) {
    __shared__ float qs[DM];
    __shared__ float hrow[DM];
    __shared__ float sc[NH][PMAX + 1];
    __shared__ int asg[PMAX];
    __shared__ int startb[32];
    __shared__ int cntb[32];

    int n = blockIdx.x, tid = threadIdx.x;
    hrow[tid] = Hg[(size_t)n * DM + tid];
    if (tid < P) asg[tid] = assign[tid];
    __syncthreads();

    // q[d] = H[n,:].Wq[d,:] + bq[d]  (Wq rows [0,DM))
    {
        const float4* wr = (const float4*)(Win + (size_t)tid * DM);
        float acc = bin[tid];
        #pragma unroll 4
        for (int k = 0; k < DM / 4; ++k) {
            float4 w = wr[k];
            acc += w.x * hrow[4*k] + w.y * hrow[4*k+1] + w.z * hrow[4*k+2] + w.w * hrow[4*k+3];
        }
        qs[tid] = acc * 0.17677669529663687f;  // 1/sqrt(32)
    }
    if (tid < B) {
        int s = 0, c = 0;
        for (int p = 0; p < P; ++p) { int a = asg[p]; s += (a < tid); c += (a == tid); }
        startb[tid] = s; cntb[tid] = c;
    }
    __syncthreads();

    // scores[h][p]
    for (int idx = tid; idx < NH * P; idx += 256) {
        int h = idx & (NH - 1), p = idx >> 3;
        const float4* kr = (const float4*)(kbuf + (size_t)p * DM + h * DHEAD);
        const float4* qh = (const float4*)(qs + h * DHEAD);
        float acc = 0.f;
        #pragma unroll
        for (int e = 0; e < DHEAD / 4; ++e) {
            float4 kv = kr[e], qv = qh[e];
            acc += qv.x * kv.x + qv.y * kv.y + qv.z * kv.z + qv.w * kv.w;
        }
        sc[h][p] = acc;
    }
    __syncthreads();

    // slice-wise softmax: thread per (b,h)
    for (int bh = tid; bh < B * NH; bh += 256) {
        int b = bh >> 3, h = bh & 7;
        int s = startb[b], c = cntb[b];
        if (c > 0) {
            float m = -INFINITY;
            for (int i = 0; i < c; ++i) m = fmaxf(m, sc[h][s + i]);
            float sum = 0.f;
            for (int i = 0; i < c; ++i) { float e = __expf(sc[h][s + i] - m); sc[h][s + i] = e; sum += e; }
            float inv = 1.0f / sum;
            for (int i = 0; i < c; ++i) sc[h][s + i] *= inv;
        }
    }
    __syncthreads();

    // ctx[b][d] for all b; empty batch -> 0
    int d = tid, h = d >> 5;
    for (int b = 0; b < B; ++b) {
        int s = startb[b], c = cntb[b];
        float acc = 0.f;
        for (int i = 0; i < c; ++i)
            acc += sc[h][s + i] * vbuf[(size_t)(s + i) * DM + d];
        ctx_out[((size_t)b * N_GENES + n) * DM + d] = acc;
    }
}

// ---- fused MFMA tail: outproj + LN1 + FFN + LN2, in-place on d_out (32 rows/block) ----
__global__ __launch_bounds__(256) void fused_tail_kernel(
    const float* __restrict__ Hg, const float* __restrict__ bout,
    const u16* __restrict__ WoB, const u16* __restrict__ W1B, const u16* __restrict__ W2B,
    const float* __restrict__ b1, const float* __restrict__ b2,
    const float* __restrict__ g1, const float* __restrict__ bb1,
    const float* __restrict__ g2, const float* __restrict__ bb2,
    const int* __restrict__ assign, float* __restrict__ io, int P, int B) {
    __shared__ u16 xb[MT][LDP];     // A storage: ctx (bf16), then x (bf16)
    __shared__ u16 hb[MT][LDP];     // hidden chunk (bf16)
    __shared__ float sb[MT][LDP];   // fp32 scratch: pre-LN dumps
    __shared__ float hasb[32];

    const f4 fzero = {0.f, 0.f, 0.f, 0.f};
    int tid = threadIdx.x;
    int wv = tid >> 6, l = tid & 63;
    int l15 = l & 15, q8 = (l >> 4) * 8, q4 = (l >> 4) * 4;
    size_t row0 = (size_t)blockIdx.x * MT;

    if (tid < B) {
        int c = 0;
        for (int p = 0; p < P; ++p) c += (assign[p] == tid);
        hasb[tid] = c ? 1.f : 0.f;
    }

    // stage ctx rows -> xb (bf16)
    for (int i = tid; i < MT * (DM / 4); i += 256) {
        int r = i >> 6, c4 = (i & 63) * 4;
        float4 v = *(const float4*)&io[(row0 + r) * DM + c4];
        xb[r][c4 + 0] = f2bf(v.x); xb[r][c4 + 1] = f2bf(v.y);
        xb[r][c4 + 2] = f2bf(v.z); xb[r][c4 + 3] = f2bf(v.w);
    }
    __syncthreads();

    // ---- GEMM0: attn_raw = ctx @ Wout^T  -> sb ----
    {
        f4 acc[2][4] = {fzero, fzero, fzero, fzero, fzero, fzero, fzero, fzero};
        for (int k0 = 0; k0 < DM; k0 += 32) {
            s8bf a0 = *(const s8bf*)&xb[l15][k0 + q8];
            s8bf a1 = *(const s8bf*)&xb[16 + l15][k0 + q8];
            #pragma unroll
            for (int nt = 0; nt < 4; ++nt) {
                int nn = wv * 64 + nt * 16 + l15;
                s8bf bf = *(const s8bf*)&WoB[(size_t)nn * DM + k0 + q8];
                acc[0][nt] = mfma_bf16(a0, bf, acc[0][nt]);
                acc[1][nt] = mfma_bf16(a1, bf, acc[1][nt]);
            }
        }
        #pragma unroll
        for (int mt = 0; mt < 2; ++mt)
            #pragma unroll
            for (int nt = 0; nt < 4; ++nt)
                #pragma unroll
                for (int r = 0; r < 4; ++r)
                    sb[mt * 16 + q4 + r][wv * 64 + nt * 16 + l15] = acc[mt][nt][r];
    }
    __syncthreads();

    // ---- LN1: t = H + has*(sb + bout); x -> xb (bf16) ----
    {
        int r = tid >> 3, cg = (tid & 7) * 32;
        size_t gr = row0 + r;
        int nIdx = (int)(gr % N_GENES), bIdx = (int)(gr / N_GENES);
        float has = hasb[bIdx];
        const float* hp = Hg + (size_t)nIdx * DM + cg;
        const float* bo = bout + cg;
        float tv[32];
        float sum = 0.f;
        #pragma unroll
        for (int j = 0; j < 32; j += 4) {
            float4 hv = *(const float4*)(hp + j);
            float4 bv = *(const float4*)(bo + j);
            float t0 = hv.x + has * (sb[r][cg + j]     + bv.x);
            float t1 = hv.y + has * (sb[r][cg + j + 1] + bv.y);
            float t2 = hv.z + has * (sb[r][cg + j + 2] + bv.z);
            float t3 = hv.w + has * (sb[r][cg + j + 3] + bv.w);
            tv[j] = t0; tv[j+1] = t1; tv[j+2] = t2; tv[j+3] = t3;
            sum += t0 + t1 + t2 + t3;
        }
        sum += __shfl_xor(sum, 1, 8); sum += __shfl_xor(sum, 2, 8); sum += __shfl_xor(sum, 4, 8);
        float mu = sum * (1.0f / DM);
        float vs = 0.f;
        #pragma unroll
        for (int j = 0; j < 32; ++j) { float dd = tv[j] - mu; vs += dd * dd; }
        vs += __shfl_xor(vs, 1, 8); vs += __shfl_xor(vs, 2, 8); vs += __shfl_xor(vs, 4, 8);
        float rs = rsqrtf(vs * (1.0f / DM) + 1e-5f);
        #pragma unroll
        for (int j = 0; j < 32; j += 2) {
            float x0 = (tv[j]     - mu) * rs * g1[cg + j]     + bb1[cg + j];
            float x1 = (tv[j + 1] - mu) * rs * g1[cg + j + 1] + bb1[cg + j + 1];
            *(u32*)&xb[r][cg + j] = (u32)f2bf(x0) | ((u32)f2bf(x1) << 16);
        }
    }
    __syncthreads();

    // ---- FFN: GEMM1 (+b1, GELU) chunked 4x256 -> hb; GEMM2 accumulates ----
    f4 acc2[2][4] = {fzero, fzero, fzero, fzero, fzero, fzero, fzero, fzero};
    for (int ch = 0; ch < 4; ++ch) {
        f4 acc1[2][4] = {fzero, fzero, fzero, fzero, fzero, fzero, fzero, fzero};
        for (int k0 = 0; k0 < DM; k0 += 32) {
            s8bf a0 = *(const s8bf*)&xb[l15][k0 + q8];
            s8bf a1 = *(const s8bf*)&xb[16 + l15][k0 + q8];
            #pragma unroll
            for (int nt = 0; nt < 4; ++nt) {
                int nn = ch * 256 + wv * 64 + nt * 16 + l15;
                s8bf bf = *(const s8bf*)&W1B[(size_t)nn * DM + k0 + q8];
                acc1[0][nt] = mfma_bf16(a0, bf, acc1[0][nt]);
                acc1[1][nt] = mfma_bf16(a1, bf, acc1[1][nt]);
            }
        }
        #pragma unroll
        for (int nt = 0; nt < 4; ++nt) {
            int cl = wv * 64 + nt * 16 + l15;
            float bb = b1[ch * 256 + cl];
            #pragma unroll
            for (int mt = 0; mt < 2; ++mt)
                #pragma unroll
                for (int r = 0; r < 4; ++r)
                    hb[mt * 16 + q4 + r][cl] = f2bf(gelu_exact(acc1[mt][nt][r] + bb));
        }
        __syncthreads();
        for (int k0 = 0; k0 < DM; k0 += 32) {
            s8bf a0 = *(const s8bf*)&hb[l15][k0 + q8];
            s8bf a1 = *(const s8bf*)&hb[16 + l15][k0 + q8];
            #pragma unroll
            for (int nt = 0; nt < 4; ++nt) {
                int nn = wv * 64 + nt * 16 + l15;
                s8bf bf = *(const s8bf*)&W2B[(size_t)nn * FF + ch * 256 + k0 + q8];
                acc2[0][nt] = mfma_bf16(a0, bf, acc2[0][nt]);
                acc2[1][nt] = mfma_bf16(a1, bf, acc2[1][nt]);
            }
        }
        __syncthreads();
    }
    #pragma unroll
    for (int mt = 0; mt < 2; ++mt)
        #pragma unroll
        for (int nt = 0; nt < 4; ++nt)
            #pragma unroll
            for (int r = 0; r < 4; ++r)
                sb[mt * 16 + q4 + r][wv * 64 + nt * 16 + l15] = acc2[mt][nt][r];
    __syncthreads();

    // ---- LN2: t = x + (ffn + b2); out -> io (fp32) ----
    {
        int r = tid >> 3, cg = (tid & 7) * 32;
        size_t gr = row0 + r;
        const float* bp = b2 + cg;
        float tv[32];
        float sum = 0.f;
        #pragma unroll
        for (int j = 0; j < 32; j += 4) {
            float4 bv = *(const float4*)(bp + j);
            float t0 = bf2f(xb[r][cg + j])     + sb[r][cg + j]     + bv.x;
            float t1 = bf2f(xb[r][cg + j + 1]) + sb[r][cg + j + 1] + bv.y;
            float t2 = bf2f(xb[r][cg + j + 2]) + sb[r][cg + j + 2] + bv.z;
            float t3 = bf2f(xb[r][cg + j + 3]) + sb[r][cg + j + 3] + bv.w;
            tv[j] = t0; tv[j+1] = t1; tv[j+2] = t2; tv[j+3] = t3;
            sum += t0 + t1 + t2 + t3;
        }
        sum += __shfl_xor(sum, 1, 8); sum += __shfl_xor(sum, 2, 8); sum += __shfl_xor(sum, 4, 8);
        float mu = sum * (1.0f / DM);
        float vs = 0.f;
        #pragma unroll
        for (int j = 0; j < 32; ++j) { float dd = tv[j] - mu; vs += dd * dd; }
        vs += __shfl_xor(vs, 1, 8); vs += __shfl_xor(vs, 2, 8); vs += __shfl_xor(vs, 4, 8);
        float rs = rsqrtf(vs * (1.0f / DM) + 1e-5f);
        float* op = io + gr * DM + cg;
        #pragma unroll
        for (int j = 0; j < 32; j += 4) {
            float4 y;
            y.x = (tv[j]     - mu) * rs * g2[cg + j]     + bb2[cg + j];
            y.y = (tv[j + 1] - mu) * rs * g2[cg + j + 1] + bb2[cg + j + 1];
            y.z = (tv[j + 2] - mu) * rs * g2[cg + j + 2] + bb2[cg + j + 2];
            y.w = (tv[j + 3] - mu) * rs * g2[cg + j + 3] + bb2[cg + j + 3];
            *(float4*)(op + j) = y;
        }
    }
}

// ================= fallback path (ws too small for weight staging): R3-proven VALU =================
__global__ __launch_bounds__(256) void attn_fb_kernel(
    const float* __restrict__ Hg, const float* __restrict__ kbuf, const float* __restrict__ vbuf,
    const int* __restrict__ assign, const float* __restrict__ Win, const float* __restrict__ bin,
    const float* __restrict__ Wout, const float* __restrict__ bout,
    const float* __restrict__ ln1g, const float* __restrict__ ln1b,
    float* __restrict__ xout, int P) {
    __shared__ float qs[DM];
    __shared__ float hrow[DM];
    __shared__ float sc[NH][PMAX + 1];
    __shared__ float ctxs[DM];
    __shared__ int asg[PMAX];
    __shared__ float red[4];

    int n = blockIdx.x, b = blockIdx.y, tid = threadIdx.x;
    if (tid < P) asg[tid] = assign[tid];
    hrow[tid] = Hg[(size_t)n * DM + tid];
    __syncthreads();
    {
        const float4* wr = (const float4*)(Win + (size_t)tid * DM);
        float acc = bin[tid];
        #pragma unroll 4
        for (int k = 0; k < DM / 4; ++k) {
            float4 w = wr[k];
            acc += w.x * hrow[4*k] + w.y * hrow[4*k+1] + w.z * hrow[4*k+2] + w.w * hrow[4*k+3];
        }
        qs[tid] = acc * 0.17677669529663687f;
        __syncthreads();
    }
    int start = 0, cnt = 0;
    for (int p = 0; p < P; ++p) { int a = asg[p]; start += (a < b); cnt += (a == b); }
    for (int idx = tid; idx < NH * cnt; idx += 256) {
        int h = idx & (NH - 1), pl = idx >> 3;
        const float* krow = kbuf + (size_t)(start + pl) * DM + h * DHEAD;
        const float* qh = qs + h * DHEAD;
        float acc = 0.f;
        #pragma unroll
        for (int e = 0; e < DHEAD; ++e) acc += qh[e] * krow[e];
        sc[h][pl] = acc;
    }
    __syncthreads();
    if (cnt > 0) {
        int h = tid >> 5, ll = tid & 31;
        float m = -INFINITY;
        for (int p = ll; p < cnt; p += 32) m = fmaxf(m, sc[h][p]);
        #pragma unroll
        for (int off = 16; off > 0; off >>= 1) m = fmaxf(m, __shfl_xor(m, off, 32));
        float s = 0.f;
        for (int p = ll; p < cnt; p += 32) { float e = __expf(sc[h][p] - m); sc[h][p] = e; s += e; }
        #pragma unroll
        for (int off = 16; off > 0; off >>= 1) s += __shfl_xor(s, off, 32);
        float inv = 1.0f / s;
        for (int p = ll; p < cnt; p += 32) sc[h][p] *= inv;
    }
    __syncthreads();
    {
        int hh = tid >> 5, e = tid & 31;
        float acc = 0.f;
        for (int p = 0; p < cnt; ++p)
            acc += sc[hh][p] * vbuf[(size_t)(start + p) * DM + hh * DHEAD + e];
        ctxs[tid] = acc;
    }
    __syncthreads();
    float ao = 0.f;
    if (cnt > 0) {
        ao = bout[tid];
        const float4* wr = (const float4*)(Wout + (size_t)tid * DM);
        #pragma unroll 4
        for (int k = 0; k < DM / 4; ++k) {
            float4 w = wr[k];
            ao += w.x * ctxs[4*k] + w.y * ctxs[4*k+1] + w.z * ctxs[4*k+2] + w.w * ctxs[4*k+3];
        }
    }
    float t = hrow[tid] + ao;
    {
        float v = t;
        #pragma unroll
        for (int off = 32; off > 0; off >>= 1) v += __shfl_down(v, off, 64);
        if ((tid & 63) == 0) red[tid >> 6] = v;
        __syncthreads();
        float mu = (red[0] + red[1] + red[2] + red[3]) * (1.0f / DM);
        __syncthreads();
        float dv = t - mu, v2 = dv * dv;
        #pragma unroll
        for (int off = 32; off > 0; off >>= 1) v2 += __shfl_down(v2, off, 64);
        if ((tid & 63) == 0) red[tid >> 6] = v2;
        __syncthreads();
        float var = (red[0] + red[1] + red[2] + red[3]) * (1.0f / DM);
        float xv = dv * rsqrtf(var + 1e-5f) * ln1g[tid] + ln1b[tid];
        xout[((size_t)b * N_GENES + n) * DM + tid] = xv;
    }
}

__global__ __launch_bounds__(256) void ffn_fb_kernel(
    float* __restrict__ xio, const float* __restrict__ W1, const float* __restrict__ b1,
    const float* __restrict__ W2, const float* __restrict__ b2,
    const float* __restrict__ ln2g, const float* __restrict__ ln2b) {
    __shared__ float xs[4][DM];
    __shared__ float hs[4][FF];
    __shared__ float red[4];
    int tid = threadIdx.x;
    size_t row0 = (size_t)blockIdx.x * 4;
    for (int i = tid; i < 4 * DM; i += 256)
        ((float*)xs)[i] = xio[row0 * DM + i];
    __syncthreads();
    for (int oi = 0; oi < FF / 256; ++oi) {
        int o = oi * 256 + tid;
        float bb = b1[o];
        float a0 = bb, a1 = bb, a2 = bb, a3 = bb;
        const float4* wr = (const float4*)(W1 + (size_t)o * DM);
        #pragma unroll 2
        for (int k = 0; k < DM / 4; ++k) {
            float4 w = wr[k];
            a0 += w.x * xs[0][4*k] + w.y * xs[0][4*k+1] + w.z * xs[0][4*k+2] + w.w * xs[0][4*k+3];
            a1 += w.x * xs[1][4*k] + w.y * xs[1][4*k+1] + w.z * xs[1][4*k+2] + w.w * xs[1][4*k+3];
            a2 += w.x * xs[2][4*k] + w.y * xs[2][4*k+1] + w.z * xs[2][4*k+2] + w.w * xs[2][4*k+3];
            a3 += w.x * xs[3][4*k] + w.y * xs[3][4*k+1] + w.z * xs[3][4*k+2] + w.w * xs[3][4*k+3];
        }
        hs[0][o] = gelu_exact(a0); hs[1][o] = gelu_exact(a1);
        hs[2][o] = gelu_exact(a2); hs[3][o] = gelu_exact(a3);
    }
    __syncthreads();
    int d = tid;
    float bb2 = b2[d];
    float c0 = bb2, c1 = bb2, c2 = bb2, c3 = bb2;
    const float4* wr = (const float4*)(W2 + (size_t)d * FF);
    #pragma unroll 2
    for (int k = 0; k < FF / 4; ++k) {
        float4 w = wr[k];
        c0 += w.x * hs[0][4*k] + w.y * hs[0][4*k+1] + w.z * hs[0][4*k+2] + w.w * hs[0][4*k+3];
        c1 += w.x * hs[1][4*k] + w.y * hs[1][4*k+1] + w.z * hs[1][4*k+2] + w.w * hs[1][4*k+3];
        c2 += w.x * hs[2][4*k] + w.y * hs[2][4*k+1] + w.z * hs[2][4*k+2] + w.w * hs[2][4*k+3];
        c3 += w.x * hs[3][4*k] + w.y * hs[3][4*k+1] + w.z * hs[3][4*k+2] + w.w * hs[3][4*k+3];
    }
    float cr[4] = {c0, c1, c2, c3};
    float g = ln2g[d], bln = ln2b[d];
    #pragma unroll
    for (int r = 0; r < 4; ++r) {
        float t = cr[r] + xs[r][d];
        float v = t;
        #pragma unroll
        for (int off = 32; off > 0; off >>= 1) v += __shfl_down(v, off, 64);
        if ((tid & 63) == 0) red[tid >> 6] = v;
        __syncthreads();
        float mu = (red[0] + red[1] + red[2] + red[3]) * (1.0f / DM);
        __syncthreads();
        float dv = t - mu, v2 = dv * dv;
        #pragma unroll
        for (int off = 32; off > 0; off >>= 1) v2 += __shfl_down(v2, off, 64);
        if ((tid & 63) == 0) red[tid >> 6] = v2;
        __syncthreads();
        float var = (red[0] + red[1] + red[2] + red[3]) * (1.0f / DM);
        float y = dv * rsqrtf(var + 1e-5f) * g + bln;
        xio[(row0 + r) * DM + d] = y;
        __syncthreads();
    }
}

extern "C" void kernel_launch(void* const* d_in, const int* in_sizes, int n_in,
                              void* d_out, int out_size, void* d_ws, size_t ws_size,
                              hipStream_t stream) {
    const float* Hg   = (const float*)d_in[0];
    const int* pidx   = (const int*)d_in[1];
    const int* assign = (const int*)d_in[2];
    const float* in_w = (const float*)d_in[4];
    const float* in_b = (const float*)d_in[5];
    const float* out_w= (const float*)d_in[6];
    const float* out_b= (const float*)d_in[7];
    const float* w1   = (const float*)d_in[8];
    const float* b1   = (const float*)d_in[9];
    const float* w2   = (const float*)d_in[10];
    const float* b2   = (const float*)d_in[11];
    const float* g1   = (const float*)d_in[12];
    const float* bb1  = (const float*)d_in[13];
    const float* g2   = (const float*)d_in[14];
    const float* bb2  = (const float*)d_in[15];

    int P = in_sizes[1];
    int B = out_size / (N_GENES * DM);
    size_t nrows = (size_t)B * N_GENES;
    float* out = (float*)d_out;

    size_t woB = (size_t)DM * DM;          // 65536
    size_t w1B = (size_t)FF * DM;          // 262144
    size_t w2B = (size_t)DM * FF;          // 262144
    size_t wbytes = (woB + w1B + w2B) * sizeof(u16);   // 1,179,648
    size_t kvbytes = 2 * (size_t)P * DM * sizeof(float);

    if (ws_size >= wbytes + kvbytes) {
        // MFMA path
        u16* WoB = (u16*)d_ws;
        u16* W1Bp = WoB + woB;
        u16* W2Bp = W1Bp + w1B;
        float* kbuf = (float*)(W2Bp + w2B);
        float* vbuf = kbuf + (size_t)P * DM;

        cvt_kernel<<<(int)((woB + 255) / 256), 256, 0, stream>>>(out_w, WoB, (int)woB);
        cvt_kernel<<<(int)((w1B + 255) / 256), 256, 0, stream>>>(w1, W1Bp, (int)w1B);
        cvt_kernel<<<(int)((w2B + 255) / 256), 256, 0, stream>>>(w2, W2Bp, (int)w2B);
        kvproj_kernel<<<P, 256, 0, stream>>>(Hg, pidx, in_w, in_b, kbuf, vbuf);
        attn_ctx_kernel<<<N_GENES, 256, 0, stream>>>(
            Hg, in_w, in_b, kbuf, vbuf, assign, out, P, B);
        fused_tail_kernel<<<(unsigned)(nrows / MT), 256, 0, stream>>>(
            Hg, out_b, WoB, W1Bp, W2Bp, b1, b2, g1, bb1, g2, bb2, assign, out, P, B);
    } else {
        // fallback: R3-proven VALU path (kv only in ws)
        float* kbuf = (float*)d_ws;
        float* vbuf = kbuf + (size_t)P * DM;
        kvproj_kernel<<<P, 256, 0, stream>>>(Hg, pidx, in_w, in_b, kbuf, vbuf);
        attn_fb_kernel<<<dim3(N_GENES, B), 256, 0, stream>>>(
            Hg, kbuf, vbuf, assign, in_w, in_b, out_w, out_b, g1, bb1, out, P);
        ffn_fb_kernel<<<(unsigned)(nrows / 4), 256, 0, stream>>>(
            out, w1, b1, w2, b2, g2, bb2);
    }
}